// Round 1
// baseline (748.361 us; speedup 1.0000x reference)
//
#include <hip/hip_runtime.h>
#include <hip/hip_bf16.h>

typedef __attribute__((ext_vector_type(8))) short short8;
typedef __attribute__((ext_vector_type(4))) float f32x4;

#define EPSB 1e-5f
#define BATCH 32
#define CIN 256
#define COUT 256
#define HW 64
#define PADW 66
#define PLANE (PADW*PADW*CIN)            // 1,115,136 bf16 elems / sample
#define KTOT 2304
#define WPS (COUT*KTOT)                  // 589,824 / sample

#define ACTP_BYTES ((size_t)BATCH*PLANE*2)          // 71,368,704
#define WW_BYTES   ((size_t)BATCH*WPS*2)            // 37,748,736
#define WS_NEED    (2*ACTP_BYTES + WW_BYTES)        // ~180.5 MB

#define GLD_LDS16(gsrc, ldst) \
  __builtin_amdgcn_global_load_lds((const __attribute__((address_space(1))) void*)(gsrc), \
                                   (__attribute__((address_space(3))) void*)(ldst), 16, 0, 0)

// ---------------- border zeroing (actp pads must be 0 every launch) ----------
__global__ void zero_borders(unsigned short* __restrict__ a1,
                             unsigned short* __restrict__ a2) {
  int p = blockIdx.x;          // 0..259 border pixels
  int b = blockIdx.y;
  int yy, xx;
  if (p < 66)       { yy = 0;          xx = p; }
  else if (p < 132) { yy = 65;         xx = p - 66; }
  else if (p < 196) { yy = p - 132 + 1; xx = 0; }
  else              { yy = p - 196 + 1; xx = 65; }
  size_t off = (size_t)b*PLANE + ((size_t)yy*PADW + xx)*CIN + threadIdx.x;
  a1[off] = 0;
  a2[off] = 0;
}

// ---------------- prep: x -> relu(bn1(x)) bf16, channel-last padded ----------
__global__ void prep1_kernel(const float* __restrict__ x,
                             const float* __restrict__ g, const float* __restrict__ be,
                             const float* __restrict__ mu, const float* __restrict__ var,
                             unsigned short* __restrict__ actp1) {
  int y = blockIdx.x;          // 0..63
  int b = blockIdx.y;
  int tid = threadIdx.x;
  int xi = tid & 63;
  int ccq = tid >> 6;          // 0..3
  size_t plane = (size_t)b * PLANE;
  const float* xb = x + (size_t)b * CIN * (HW*HW) + (size_t)y * HW;
  for (int it = 0; it < 8; ++it) {
    int cc = ccq + 4*it;       // 0..31 chunk of 8 channels
    int c0 = cc * 8;
    union { unsigned short u[8]; short8 v; } pk;
    #pragma unroll
    for (int j = 0; j < 8; ++j) {
      int c = c0 + j;
      float inv = g[c] * rsqrtf(var[c] + EPSB);
      float add = be[c] - mu[c] * inv;
      float v = fmaf(xb[(size_t)c * (HW*HW) + xi], inv, add);
      v = fmaxf(v, 0.0f);
      __hip_bfloat16 t = __float2bfloat16(v);
      pk.u[j] = *reinterpret_cast<unsigned short*>(&t);
    }
    size_t off = plane + ((size_t)(y+1)*PADW + (xi+1))*CIN + c0;
    *reinterpret_cast<short8*>(actp1 + off) = pk.v;
  }
}

// ---------------- per-sample weight gen: wW[b][co][kappa], bf16 --------------
// kappa = s*288 + kk*32 + c  (s=ci>>5, c=ci&31, kk=ky*3+kx)
__global__ void genw_kernel(const float* __restrict__ w, const float* __restrict__ bias,
                            const float* __restrict__ hin, unsigned short* __restrict__ wW) {
  int b = blockIdx.y;
  float h = 0.5f + hin[b] * (1.0f/64.0f);
  int co = blockIdx.x / 9;
  int kap = (blockIdx.x % 9) * 256 + threadIdx.x;
  int s = kap / 288;
  int r = kap - s*288;
  int kk = r >> 5;
  int c  = r & 31;
  int ci = s*32 + c;
  int src = (co*256 + ci)*9 + kk;
  float v = fmaf(h, w[src], bias[src]);
  __hip_bfloat16 t = __float2bfloat16(v);
  wW[(size_t)b*WPS + (size_t)co*KTOT + kap] = *reinterpret_cast<unsigned short*>(&t);
}

// ---------------- implicit-GEMM conv, 128x128 tile, 4 waves ------------------
template<int LAYER>
__global__ __launch_bounds__(256) void conv_kernel(
    const unsigned short* __restrict__ actp,
    const unsigned short* __restrict__ wW,
    const float* __restrict__ g2, const float* __restrict__ be2,
    const float* __restrict__ mu2, const float* __restrict__ var2,
    unsigned short* __restrict__ actp_out,
    const float* __restrict__ xin, float* __restrict__ out) {
  __shared__ unsigned short wtile[128*32];     // 8 KB
  __shared__ unsigned short atile[4*66*32];    // 16.9 KB

  int wg = blockIdx.x;                         // 2048 blocks; 2048%8==0 -> simple bijective XCD swizzle
  int lin = ((wg & 7) << 8) + (wg >> 3);
  int b  = lin >> 6;
  int mt = (lin >> 5) & 1;
  int nt = lin & 31;
  int y0 = nt * 2;

  int tid = threadIdx.x;
  int lane = tid & 63;
  int wv = tid >> 6;
  int wm = wv >> 1, wn = wv & 1;
  int lhi = lane >> 4;
  int llo = lane & 15;

  const unsigned short* ab = actp + (size_t)b * PLANE;
  const unsigned short* wb = wW + (size_t)b * WPS + (size_t)mt * 128 * KTOT;

  // act staging: tile [ry<4][xx<66][ci<32], linear LDS; source pre-swizzled (T21)
  int a_src[5]; int a_on[5];
  #pragma unroll
  for (int t = 0; t < 5; ++t) {
    int e = (t*256 + tid) * 8;
    a_on[t] = (e < 4*66*32);
    int ee = a_on[t] ? e : 0;
    int pix = ee >> 5;                 // ry*66+xx
    int chS = (ee >> 3) & 3;
    int ry = pix / 66;
    int xx = pix - ry*66;
    int chL = chS ^ ((xx >> 2) & 3);   // inverse swizzle on source
    a_src[t] = ((y0 + ry)*66 + xx)*256 + chL*8;   // + s*32 per slice
  }
  // weight staging: subtile [co<128][c<32]
  int w_src[2];
  #pragma unroll
  for (int t = 0; t < 2; ++t) {
    int e = (t*256 + tid) * 8;
    int co = e >> 5;
    int chS = (e >> 3) & 3;
    int chL = chS ^ ((co >> 2) & 3);
    w_src[t] = co*KTOT + chL*8;        // + kap0 per phase
  }
  // weight frag byte offsets (swizzled read)
  int wf_off[4];
  #pragma unroll
  for (int mb = 0; mb < 4; ++mb) {
    int co = wm*64 + mb*16 + llo;
    wf_off[mb] = ((co*32 + 8*lhi) * 2) ^ (((co >> 2) & 3) << 4);
  }
  int xv[4];
  #pragma unroll
  for (int nb = 0; nb < 4; ++nb) xv[nb] = nb*16 + llo;   // pixel x (row = y0+wn)

  f32x4 acc[4][4];
  #pragma unroll
  for (int i = 0; i < 4; ++i)
    #pragma unroll
    for (int j = 0; j < 4; ++j) acc[i][j] = (f32x4)0.0f;

  #pragma unroll 1
  for (int s = 0; s < 8; ++s) {
    #pragma unroll
    for (int t = 0; t < 5; ++t) {
      if (a_on[t])
        GLD_LDS16(ab + a_src[t] + s*32, atile + (t*256 + wv*64)*8);
    }
    #pragma unroll
    for (int kk = 0; kk < 9; ++kk) {
      int ky = kk / 3, kx = kk - (kk/3)*3;
      int kap0 = s*288 + kk*32;
      GLD_LDS16(wb + w_src[0] + kap0, wtile + (0*256 + wv*64)*8);
      GLD_LDS16(wb + w_src[1] + kap0, wtile + (1*256 + wv*64)*8);
      __syncthreads();
      short8 af[4], bf[4];
      #pragma unroll
      for (int mb = 0; mb < 4; ++mb)
        af[mb] = *reinterpret_cast<const short8*>(
            reinterpret_cast<const char*>(wtile) + wf_off[mb]);
      #pragma unroll
      for (int nb = 0; nb < 4; ++nb) {
        int xx = xv[nb] + kx;
        int byt = (((wn + ky)*66 + xx)*32 + 8*lhi) * 2;
        byt ^= ((xx >> 2) & 3) << 4;
        bf[nb] = *reinterpret_cast<const short8*>(
            reinterpret_cast<const char*>(atile) + byt);
      }
      #pragma unroll
      for (int mb = 0; mb < 4; ++mb)
        #pragma unroll
        for (int nb = 0; nb < 4; ++nb)
          acc[mb][nb] = __builtin_amdgcn_mfma_f32_16x16x32_bf16(af[mb], bf[nb], acc[mb][nb], 0, 0, 0);
      __syncthreads();
    }
  }

  int y = y0 + wn;
  if (LAYER == 1) {
    unsigned short* ob = actp_out + (size_t)b * PLANE;
    #pragma unroll
    for (int mb = 0; mb < 4; ++mb) {
      int co0 = mt*128 + wm*64 + mb*16 + 4*lhi;
      float inv[4], add[4];
      #pragma unroll
      for (int r = 0; r < 4; ++r) {
        int c = co0 + r;
        inv[r] = g2[c] * rsqrtf(var2[c] + EPSB);
        add[r] = be2[c] - mu2[c] * inv[r];
      }
      #pragma unroll
      for (int nb = 0; nb < 4; ++nb) {
        size_t off = ((size_t)(y+1)*PADW + (xv[nb]+1))*CIN + co0;
        unsigned long long pv = 0;
        #pragma unroll
        for (int r = 0; r < 4; ++r) {
          float v = fmaf(acc[mb][nb][r], inv[r], add[r]);
          v = fmaxf(v, 0.0f);
          __hip_bfloat16 t = __float2bfloat16(v);
          pv |= (unsigned long long)(*reinterpret_cast<unsigned short*>(&t)) << (16*r);
        }
        *reinterpret_cast<unsigned long long*>(ob + off) = pv;
      }
    }
  } else {
    #pragma unroll
    for (int mb = 0; mb < 4; ++mb) {
      int co0 = mt*128 + wm*64 + mb*16 + 4*lhi;
      #pragma unroll
      for (int r = 0; r < 4; ++r) {
        int co = co0 + r;
        size_t base = (((size_t)b*COUT + co)*HW + y)*HW;
        #pragma unroll
        for (int nb = 0; nb < 4; ++nb) {
          int xp = xv[nb];
          out[base + xp] = acc[mb][nb][r] + xin[base + xp];
        }
      }
    }
  }
}

extern "C" void kernel_launch(void* const* d_in, const int* in_sizes, int n_in,
                              void* d_out, int out_size, void* d_ws, size_t ws_size,
                              hipStream_t stream) {
  const float* x   = (const float*)d_in[0];
  const float* hin = (const float*)d_in[1];
  const float* g1  = (const float*)d_in[2];
  const float* be1 = (const float*)d_in[3];
  const float* mu1 = (const float*)d_in[4];
  const float* va1 = (const float*)d_in[5];
  const float* w1  = (const float*)d_in[6];
  const float* b1  = (const float*)d_in[7];
  const float* g2  = (const float*)d_in[8];
  const float* be2 = (const float*)d_in[9];
  const float* mu2 = (const float*)d_in[10];
  const float* va2 = (const float*)d_in[11];
  const float* w2  = (const float*)d_in[12];
  const float* b2  = (const float*)d_in[13];
  float* out = (float*)d_out;

  if (ws_size < WS_NEED) return;   // insufficient scratch; cannot run safely

  unsigned short* actp1 = (unsigned short*)d_ws;
  unsigned short* actp2 = (unsigned short*)((char*)d_ws + ACTP_BYTES);
  unsigned short* wW    = (unsigned short*)((char*)d_ws + 2*ACTP_BYTES);

  zero_borders<<<dim3(260, 32), 256, 0, stream>>>(actp1, actp2);
  prep1_kernel<<<dim3(64, 32), 256, 0, stream>>>(x, g1, be1, mu1, va1, actp1);
  genw_kernel<<<dim3(2304, 32), 256, 0, stream>>>(w1, b1, hin, wW);
  conv_kernel<1><<<2048, 256, 0, stream>>>(actp1, wW, g2, be2, mu2, va2, actp2, nullptr, nullptr);
  genw_kernel<<<dim3(2304, 32), 256, 0, stream>>>(w2, b2, hin, wW);
  conv_kernel<2><<<2048, 256, 0, stream>>>(actp2, wW, nullptr, nullptr, nullptr, nullptr, nullptr, x, out);
}